// Round 4
// baseline (502.238 us; speedup 1.0000x reference)
//
#include <hip/hip_runtime.h>

#define VOC 49408
#define TD 512
#define DM 768
#define NCOLG 386   // VOC / 128
#define NTILES 772  // VOC / 64
#define PV_SPLITS 32

typedef __attribute__((ext_vector_type(8))) short bf16x8;
typedef __attribute__((ext_vector_type(4))) float f32x4;

__device__ __forceinline__ unsigned short f2bf(float f) {
  unsigned int u = __float_as_uint(f);
  u += 0x7fffu + ((u >> 16) & 1u);   // RNE
  return (unsigned short)(u >> 16);
}

__device__ __forceinline__ float bf2f(unsigned short h) {
  return __uint_as_float(((unsigned int)h) << 16);
}

__device__ __forceinline__ void gload16(const void* g, const void* l) {
  __builtin_amdgcn_global_load_lds(
      (const __attribute__((address_space(1))) void*)g,
      (__attribute__((address_space(3))) void*)l, 16, 0, 0);
}

// ---------------------------------------------------------------- K1: proj + normalize
__global__ __launch_bounds__(256) void k_proj(const float* __restrict__ kw,
                                              const float* __restrict__ Wp,
                                              const float* __restrict__ bp,
                                              unsigned short* __restrict__ kwn) {
  __shared__ float row_lds[4 * DM];
  __shared__ float rsum[4][4];
  __shared__ float rinv_s[4];
  const int t = threadIdx.x;
  const int rb = blockIdx.x * 4;
  for (int i = 0; i < 12; ++i) {
    int idx = i * 256 + t;
    row_lds[idx] = kw[(size_t)rb * DM + idx];
  }
  __syncthreads();
  float acc[4][2] = {};
  for (int m = 0; m < DM; ++m) {
    float w0 = Wp[m * TD + t];
    float w1 = Wp[m * TD + t + 256];
#pragma unroll
    for (int r = 0; r < 4; ++r) {
      float kv = row_lds[r * DM + m];
      acc[r][0] = fmaf(kv, w0, acc[r][0]);
      acc[r][1] = fmaf(kv, w1, acc[r][1]);
    }
  }
  const float b0 = bp[t], b1 = bp[t + 256];
  float p[4];
#pragma unroll
  for (int r = 0; r < 4; ++r) {
    acc[r][0] += b0;
    acc[r][1] += b1;
    p[r] = acc[r][0] * acc[r][0] + acc[r][1] * acc[r][1];
  }
#pragma unroll
  for (int off = 32; off; off >>= 1) {
#pragma unroll
    for (int r = 0; r < 4; ++r) p[r] += __shfl_down(p[r], off);
  }
  const int lane = t & 63, wv = t >> 6;
  if (lane == 0) {
#pragma unroll
    for (int r = 0; r < 4; ++r) rsum[r][wv] = p[r];
  }
  __syncthreads();
  if (t < 4) {
    float s = rsum[t][0] + rsum[t][1] + rsum[t][2] + rsum[t][3];
    rinv_s[t] = 1.0f / fmaxf(sqrtf(s), 1e-8f);
  }
  __syncthreads();
#pragma unroll
  for (int r = 0; r < 4; ++r) {
    float ri = rinv_s[r];
    kwn[(size_t)(rb + r) * TD + t] = f2bf(acc[r][0] * ri);
    kwn[(size_t)(rb + r) * TD + t + 256] = f2bf(acc[r][1] * ri);
  }
}

// ---------------------------------------------------------------- K2: emb normalize
__global__ __launch_bounds__(64) void k_embnorm(const float* __restrict__ We,
                                                unsigned short* __restrict__ embn) {
  const int v = blockIdx.x;
  const int t = threadIdx.x;
  const float* rowp = We + (size_t)v * TD;
  float4 a = *(const float4*)(rowp + t * 8);
  float4 b = *(const float4*)(rowp + t * 8 + 4);
  float ss = a.x * a.x + a.y * a.y + a.z * a.z + a.w * a.w +
             b.x * b.x + b.y * b.y + b.z * b.z + b.w * b.w;
#pragma unroll
  for (int off = 1; off < 64; off <<= 1) ss += __shfl_xor(ss, off);
  const float ri = 1.0f / fmaxf(sqrtf(ss), 1e-8f);
  bf16x8 o;
  o[0] = (short)f2bf(a.x * ri); o[1] = (short)f2bf(a.y * ri);
  o[2] = (short)f2bf(a.z * ri); o[3] = (short)f2bf(a.w * ri);
  o[4] = (short)f2bf(b.x * ri); o[5] = (short)f2bf(b.y * ri);
  o[6] = (short)f2bf(b.z * ri); o[7] = (short)f2bf(b.w * ri);
  *(bf16x8*)(embn + (size_t)v * TD + t * 8) = o;
}

// ---------------------------------------------------------------- K2b: transpose RAW W_emb -> embT bf16 [d][v]
__global__ __launch_bounds__(256) void k_transpose(const float* __restrict__ We,
                                                   unsigned short* __restrict__ embT) {
  __shared__ unsigned short tile[64 * 72];
  const int t = threadIdx.x;
  const int d0 = blockIdx.x * 64, v0 = blockIdx.y * 64;
#pragma unroll
  for (int i = 0; i < 4; ++i) {
    int vl = i * 16 + (t >> 4), c = t & 15;
    float4 f = *(const float4*)(We + (size_t)(v0 + vl) * TD + d0 + c * 4);
    unsigned short* dst = &tile[vl * 72 + c * 4];
    dst[0] = f2bf(f.x); dst[1] = f2bf(f.y); dst[2] = f2bf(f.z); dst[3] = f2bf(f.w);
  }
  __syncthreads();
#pragma unroll
  for (int p = 0; p < 2; ++p) {
    int dl = p * 32 + (t >> 3), vch = t & 7;
    bf16x8 o;
#pragma unroll
    for (int i = 0; i < 8; ++i) o[i] = (short)tile[(vch * 8 + i) * 72 + dl];
    *(bf16x8*)(embT + (size_t)(d0 + dl) * VOC + v0 + vch * 8) = o;
  }
}

// ---------------------------------------------------------------- K3: cos GEMM + sumexp partials + e=bf16(exp(cos))
// grid (8 rowg, 386 colg). LDS: As/Bs (32KB) aliased by els (34.8KB) in epilogue.
__global__ __launch_bounds__(256) void k_cos(const unsigned short* __restrict__ kwn,
                                             const unsigned short* __restrict__ embn,
                                             float* __restrict__ cosd,
                                             unsigned short* __restrict__ eout,
                                             float* __restrict__ partial) {
  __shared__ unsigned short smem[18432];   // 36 KB
  unsigned short* As = smem;               // 128*64
  unsigned short* Bs = smem + 8192;        // 128*64
  unsigned short* els = smem;              // 128 x 136 (epilogue alias, 17408 ushorts)
  __shared__ float rs[2][128];
  const int t = threadIdx.x;
  const int rowg = blockIdx.x, colg = blockIdx.y;
  const int lane = t & 63, w = t >> 6;
  const int wm = w >> 1, wn = w & 1;
  const int g = lane >> 4, l15 = lane & 15;

  f32x4 acc[4][4];
#pragma unroll
  for (int mi = 0; mi < 4; ++mi)
#pragma unroll
    for (int ni = 0; ni < 4; ++ni)
#pragma unroll
      for (int j = 0; j < 4; ++j) acc[mi][ni][j] = 0.0f;

  const unsigned short* Ab = kwn + (size_t)rowg * 128 * TD + (size_t)(t >> 3) * TD + (t & 7) * 8;
  const unsigned short* Bb = embn + (size_t)colg * 128 * TD + (size_t)(t >> 3) * TD + (t & 7) * 8;

  for (int kt = 0; kt < 8; ++kt) {
#pragma unroll
    for (int i = 0; i < 4; ++i) {
      gload16(Ab + (size_t)(i * 32) * TD + kt * 64, (const void*)(As + i * 2048 + w * 512));
      gload16(Bb + (size_t)(i * 32) * TD + kt * 64, (const void*)(Bs + i * 2048 + w * 512));
    }
    __syncthreads();
#pragma unroll
    for (int ks = 0; ks < 2; ++ks) {
      bf16x8 a[4], b[4];
#pragma unroll
      for (int mi = 0; mi < 4; ++mi)
        a[mi] = *(const bf16x8*)&As[(wm * 64 + mi * 16 + l15) * 64 + ks * 32 + g * 8];
#pragma unroll
      for (int ni = 0; ni < 4; ++ni)
        b[ni] = *(const bf16x8*)&Bs[(wn * 64 + ni * 16 + l15) * 64 + ks * 32 + g * 8];
#pragma unroll
      for (int mi = 0; mi < 4; ++mi)
#pragma unroll
        for (int ni = 0; ni < 4; ++ni)
          acc[mi][ni] =
              __builtin_amdgcn_mfma_f32_16x16x32_bf16(a[mi], b[ni], acc[mi][ni], 0, 0, 0);
    }
    __syncthreads();
  }

  __syncthreads();  // last MFMA's As/Bs reads done -> els may alias

  const size_t rowbase = (size_t)rowg * 128 + wm * 64;
  const int colbase = colg * 128 + wn * 64;
#pragma unroll
  for (int mi = 0; mi < 4; ++mi) {
    float es[4] = {0.f, 0.f, 0.f, 0.f};
#pragma unroll
    for (int ni = 0; ni < 4; ++ni) {
#pragma unroll
      for (int j = 0; j < 4; ++j) {
        float c = acc[mi][ni][j];
        cosd[(rowbase + mi * 16 + g * 4 + j) * VOC + colbase + ni * 16 + l15] = c;
        float ev = __expf(c);
        es[j] += ev;
        els[(wm * 64 + mi * 16 + g * 4 + j) * 136 + wn * 64 + ni * 16 + l15] = f2bf(ev);
      }
    }
#pragma unroll
    for (int j = 0; j < 4; ++j) {
      float e = es[j];
      e += __shfl_xor(e, 1);
      e += __shfl_xor(e, 2);
      e += __shfl_xor(e, 4);
      e += __shfl_xor(e, 8);
      if (l15 == 0) rs[wn][wm * 64 + mi * 16 + g * 4 + j] = e;
    }
  }
  __syncthreads();
  if (t < 128) {
    float srow = rs[0][t] + rs[1][t];
    partial[(size_t)colg * 1024 + rowg * 128 + t] = srow;
  }
  // cooperative e store: 128 rows x 128 cols bf16
#pragma unroll
  for (int k = 0; k < 8; ++k) {
    int id = k * 256 + t;
    int rr = id >> 4, cc = id & 15;
    bf16x8 v = *(const bf16x8*)&els[rr * 136 + cc * 8];
    *(bf16x8*)(eout + (size_t)(rowg * 128 + rr) * VOC + colg * 128 + cc * 8) = v;
  }
}

// ---------------------------------------------------------------- K3b: denom reduce
__global__ __launch_bounds__(256) void k_denom(const float* __restrict__ partial,
                                               float* __restrict__ rdenom) {
  const int row = blockIdx.x * 256 + threadIdx.x;
  float s = 0.f;
  for (int gI = 0; gI < NCOLG; ++gI) s += partial[(size_t)gI * 1024 + row];
  rdenom[row] = 1.0f / s;
}

// ---------------------------------------------------------------- K4: PV GEMM on e (gload16 A+B) + prob write
// BM=128, BN=256, BK=64. grid 512 decoded so co-resident (id, id+256) differ in colg.
__global__ __launch_bounds__(256, 2) void k_pv(const unsigned short* __restrict__ e,
                                               const unsigned short* __restrict__ embT,
                                               const float* __restrict__ rdenom,
                                               float* __restrict__ prob,
                                               float* __restrict__ kpart) {
  __shared__ unsigned short As[128 * 64];   // 16 KB, LDS[r][c]=G[r][c^(r&7)]
  __shared__ unsigned short Bs[256 * 64];   // 32 KB, same swizzle
  const int t = threadIdx.x;
  const int lane = t & 63, w = t >> 6;        // 4 waves
  const int wr = w >> 1, wc = w & 1;          // per-wave 64 rows x 128 d
  const int g = lane >> 4, l15 = lane & 15;

  const int id = blockIdx.x;                  // 0..511
  const int rowg = (id >> 1) & 7;
  const int s = (id >> 4) & 31;
  const int colg = (id ^ (id >> 8)) & 1;
  const int t0 = s * 24 + (s < 4 ? s : 4);
  const int t1 = t0 + 24 + (s < 4 ? 1 : 0);

  // staging lane constants (shared by A and B gloads)
  const int brow_l = lane >> 3;               // 0..7
  const int bsl = (lane & 7) ^ brow_l;        // pre-swizzled source chunk

  // prob-path constants
  const int ar = t >> 1, ah = t & 1;
  const int grow = rowg * 128 + ar;
  const float rdv = (colg == 0) ? rdenom[grow] : 0.0f;
  float* pbase = prob + (size_t)grow * VOC;

  f32x4 acc[4][8];
#pragma unroll
  for (int mi = 0; mi < 4; ++mi)
#pragma unroll
    for (int ni = 0; ni < 8; ++ni)
#pragma unroll
      for (int j = 0; j < 4; ++j) acc[mi][ni][j] = 0.0f;

  for (int kt = t0; kt < t1; ++kt) {
    const int v0 = kt * 64;
    __syncthreads();  // previous tile's LDS reads done

    // stage A (e rows rowg*128..+128): 4 gloads
#pragma unroll
    for (int i = 0; i < 4; ++i) {
      gload16(e + (size_t)(rowg * 128 + i * 32 + w * 8 + brow_l) * VOC + v0 + bsl * 8,
              (const void*)(As + (i * 32 + w * 8) * 64));
    }
    // stage B (embT rows colg*256..+256): 8 gloads
#pragma unroll
    for (int i = 0; i < 8; ++i) {
      gload16(embT + (size_t)(colg * 256 + i * 32 + w * 8 + brow_l) * VOC + v0 + bsl * 8,
              (const void*)(Bs + (i * 32 + w * 8) * 64));
    }

    __syncthreads();  // A+B resident

    // MFMA: wave (wr,wc) rows [wr*64,+64) x d [wc*128,+128)
#pragma unroll
    for (int ks = 0; ks < 2; ++ks) {
      const int ch = (((ks * 4 + g) ^ (l15 & 7)) << 3);
      bf16x8 a[4];
#pragma unroll
      for (int mi = 0; mi < 4; ++mi)
        a[mi] = *(const bf16x8*)&As[(wr * 64 + mi * 16 + l15) * 64 + ch];
#pragma unroll
      for (int ni = 0; ni < 8; ++ni) {
        bf16x8 b = *(const bf16x8*)&Bs[(wc * 128 + ni * 16 + l15) * 64 + ch];
#pragma unroll
        for (int mi = 0; mi < 4; ++mi)
          acc[mi][ni] = __builtin_amdgcn_mfma_f32_16x16x32_bf16(a[mi], b, acc[mi][ni], 0, 0, 0);
      }
    }

    // prob = f32(e)*rdv from the resident A tile (colg 0 only)
    if (colg == 0) {
#pragma unroll
      for (int j = 0; j < 4; ++j) {
        const int c = ah * 4 + j;
        bf16x8 ev = *(const bf16x8*)&As[ar * 64 + ((c ^ (ar & 7)) << 3)];
        float4 o0, o1;
        o0.x = bf2f((unsigned short)ev[0]) * rdv;
        o0.y = bf2f((unsigned short)ev[1]) * rdv;
        o0.z = bf2f((unsigned short)ev[2]) * rdv;
        o0.w = bf2f((unsigned short)ev[3]) * rdv;
        o1.x = bf2f((unsigned short)ev[4]) * rdv;
        o1.y = bf2f((unsigned short)ev[5]) * rdv;
        o1.z = bf2f((unsigned short)ev[6]) * rdv;
        o1.w = bf2f((unsigned short)ev[7]) * rdv;
        *(float4*)(pbase + v0 + c * 8) = o0;
        *(float4*)(pbase + v0 + c * 8 + 4) = o1;
      }
    }
  }

  // epilogue: kpart[s][row][d] (unnormalized; rdv applied in k_kwout)
#pragma unroll
  for (int mi = 0; mi < 4; ++mi)
#pragma unroll
    for (int ni = 0; ni < 8; ++ni)
#pragma unroll
      for (int j = 0; j < 4; ++j)
        kpart[((size_t)s * 1024 + rowg * 128 + wr * 64 + mi * 16 + g * 4 + j) * TD +
              colg * 256 + wc * 128 + ni * 16 + l15] = acc[mi][ni][j];
}

// ---------------------------------------------------------------- K5: kw_out reduce (+rdv)
__global__ __launch_bounds__(256) void k_kwout(const float* __restrict__ kpart,
                                               const float* __restrict__ rdenom,
                                               float* __restrict__ outp) {
  const int idx = blockIdx.x * 256 + threadIdx.x;
  const int row = idx >> 9;
  float s = 0.f;
#pragma unroll
  for (int sp = 0; sp < PV_SPLITS; ++sp) s += kpart[(size_t)sp * 524288 + idx];
  outp[idx] = s * rdenom[row];
}

extern "C" void kernel_launch(void* const* d_in, const int* in_sizes, int n_in,
                              void* d_out, int out_size, void* d_ws, size_t ws_size,
                              hipStream_t stream) {
  const float* kw = (const float*)d_in[0];
  const float* Wp = (const float*)d_in[1];
  const float* bp = (const float*)d_in[2];
  const float* We = (const float*)d_in[3];
  float* out = (float*)d_out;
  char* ws = (char*)d_ws;

  // ws layout, all disjoint (~260 MB; fill-size evidence => ws >= ~1.2 GB)
  unsigned short* embT = (unsigned short*)ws;                       // 50,593,792
  unsigned short* kwn = (unsigned short*)(ws + 50593792);           // 1,048,576
  unsigned short* embn = (unsigned short*)(ws + 51642368);          // 50,593,792
  float* partial = (float*)(ws + 102236160);                        // 1,581,056
  float* rdenom = (float*)(ws + 103817216);                         // 4,096
  unsigned short* e = (unsigned short*)(ws + 103821312);            // 101,187,584
  float* kpart = (float*)(ws + 205008896);                          // 67,108,864

  float* kwout = out;
  float* prob = out + 524288;
  float* cosd = out + 51118080;

  hipLaunchKernelGGL(k_proj, dim3(256), dim3(256), 0, stream, kw, Wp, bp, kwn);
  hipLaunchKernelGGL(k_embnorm, dim3(VOC), dim3(64), 0, stream, We, embn);
  hipLaunchKernelGGL(k_transpose, dim3(8, 772), dim3(256), 0, stream, We, embT);
  hipLaunchKernelGGL(k_cos, dim3(8, NCOLG), dim3(256), 0, stream, kwn, embn, cosd, e, partial);
  hipLaunchKernelGGL(k_denom, dim3(4), dim3(256), 0, stream, partial, rdenom);
  hipLaunchKernelGGL(k_pv, dim3(512), dim3(256), 0, stream, e, embT, rdenom, prob, kpart);
  hipLaunchKernelGGL(k_kwout, dim3(2048), dim3(256), 0, stream, kpart, rdenom, kwout);
}